// Round 1
// baseline (1201.884 us; speedup 1.0000x reference)
//
#include <hip/hip_runtime.h>
#include <math.h>

#define N_NODES 100000
#define N_EDGES 3200000
#define IN_DIM  128
#define HID     64

// ---------------------------------------------------------------------------
// gemm1: xl = x @ W1_l   (N x 64)
//        xr = x @ W1_r + b1 (N x 64)
// W1_l and W1_r combined into one [128][128] LDS tile (64 KB).
// Block = 256 threads, 8 rows of x per block, 4 output cols per thread.
// x row elements read via global broadcast (L1-served, 2 addrs per wave).
// ---------------------------------------------------------------------------
__global__ __launch_bounds__(256) void gemm1(const float* __restrict__ x,
                                             const float* __restrict__ Wl,
                                             const float* __restrict__ Wr,
                                             const float* __restrict__ b1,
                                             float* __restrict__ xl,
                                             float* __restrict__ xr) {
    __shared__ float Wc[IN_DIM][128];  // cols 0..63 = W1_l, 64..127 = W1_r
    const int tid = threadIdx.x;

    // cooperative load of both weight matrices into LDS
    for (int idx = tid * 4; idx < IN_DIM * 128; idx += 256 * 4) {
        const int row = idx >> 7;
        const int col = idx & 127;
        float4 v;
        if (col < 64) v = *(const float4*)&Wl[row * 64 + col];
        else          v = *(const float4*)&Wr[row * 64 + (col - 64)];
        *(float4*)&Wc[row][col] = v;
    }
    __syncthreads();

    const int row  = tid >> 5;          // 0..7
    const int c4   = (tid & 31) * 4;    // 0,4,...,124
    const int node = blockIdx.x * 8 + row;
    if (node >= N_NODES) return;

    const float* xrow = x + (size_t)node * IN_DIM;
    float a0 = 0.f, a1 = 0.f, a2 = 0.f, a3 = 0.f;
    #pragma unroll 8
    for (int k = 0; k < IN_DIM; ++k) {
        const float xv = xrow[k];                       // broadcast (L1)
        const float4 w = *(const float4*)&Wc[k][c4];    // ds_read_b128
        a0 += xv * w.x; a1 += xv * w.y; a2 += xv * w.z; a3 += xv * w.w;
    }

    if (c4 < 64) {
        float4 o = {a0, a1, a2, a3};
        *(float4*)&xl[(size_t)node * HID + c4] = o;
    } else {
        const int c = c4 - 64;
        const float4 bb = *(const float4*)&b1[c];
        float4 o = {a0 + bb.x, a1 + bb.y, a2 + bb.z, a3 + bb.w};
        *(float4*)&xr[(size_t)node * HID + c] = o;
    }
}

// ---------------------------------------------------------------------------
// scatter1: one wave per edge. lane k: agg1[dst][k] += xl[src][k]; lane0 degs.
// ---------------------------------------------------------------------------
__global__ __launch_bounds__(256) void scatter1(const int* __restrict__ ei,
                                                const float* __restrict__ xl,
                                                float* __restrict__ agg1,
                                                float* __restrict__ deg) {
    const int gid  = blockIdx.x * 256 + threadIdx.x;
    const int e    = gid >> 6;
    const int lane = gid & 63;
    if (e >= N_EDGES) return;
    const int src = ei[e];
    const int dst = ei[N_EDGES + e];
    unsafeAtomicAdd(&agg1[(size_t)dst * HID + lane], xl[(size_t)src * HID + lane]);
    if (lane == 0) unsafeAtomicAdd(&deg[dst], 1.0f);
}

// ---------------------------------------------------------------------------
// deginv: deg -> deg_inv in place
// ---------------------------------------------------------------------------
__global__ __launch_bounds__(256) void deginv(float* __restrict__ deg) {
    const int i = blockIdx.x * 256 + threadIdx.x;
    if (i >= N_NODES) return;
    const float d = deg[i];
    deg[i] = (d > 0.f) ? (1.0f / d) : 0.f;
}

// ---------------------------------------------------------------------------
// nodeC: wave per node. h = relu(agg1*deg_inv + xr); hl = h.W2_l; hr = h.W2_r + b2
// ---------------------------------------------------------------------------
__global__ __launch_bounds__(256) void nodeC(const float* __restrict__ agg1,
                                             const float* __restrict__ xr,
                                             const float* __restrict__ deg_inv,
                                             const float* __restrict__ w2l,
                                             const float* __restrict__ w2r,
                                             const float* __restrict__ b2,
                                             float* __restrict__ hl,
                                             float* __restrict__ hr) {
    const int gid  = blockIdx.x * 256 + threadIdx.x;
    const int node = gid >> 6;
    const int lane = gid & 63;
    if (node >= N_NODES) return;
    const float di = deg_inv[node];
    float h = agg1[(size_t)node * HID + lane] * di + xr[(size_t)node * HID + lane];
    h = fmaxf(h, 0.f);
    float a = h * w2l[lane];
    float b = h * w2r[lane];
    #pragma unroll
    for (int off = 32; off; off >>= 1) {
        a += __shfl_xor(a, off);
        b += __shfl_xor(b, off);
    }
    if (lane == 0) {
        hl[node] = a;
        hr[node] = b + b2[0];
    }
}

// ---------------------------------------------------------------------------
// scatter2: one thread per edge: agg2[dst] += hl[src]
// ---------------------------------------------------------------------------
__global__ __launch_bounds__(256) void scatter2(const int* __restrict__ ei,
                                                const float* __restrict__ hl,
                                                float* __restrict__ agg2) {
    const int e = blockIdx.x * 256 + threadIdx.x;
    if (e >= N_EDGES) return;
    unsafeAtomicAdd(&agg2[ei[N_EDGES + e]], hl[ei[e]]);
}

// ---------------------------------------------------------------------------
// outk: out = sigmoid(agg2*deg_inv + hr)
// ---------------------------------------------------------------------------
__global__ __launch_bounds__(256) void outk(const float* __restrict__ agg2,
                                            const float* __restrict__ deg_inv,
                                            const float* __restrict__ hr,
                                            float* __restrict__ out) {
    const int i = blockIdx.x * 256 + threadIdx.x;
    if (i >= N_NODES) return;
    const float z = agg2[i] * deg_inv[i] + hr[i];
    out[i] = 1.0f / (1.0f + expf(-z));
}

extern "C" void kernel_launch(void* const* d_in, const int* in_sizes, int n_in,
                              void* d_out, int out_size, void* d_ws, size_t ws_size,
                              hipStream_t stream) {
    const float* x    = (const float*)d_in[0];
    const int*   ei   = (const int*)  d_in[1];
    const float* W1l  = (const float*)d_in[2];
    const float* b1   = (const float*)d_in[3];
    const float* W1r  = (const float*)d_in[4];
    const float* W2l  = (const float*)d_in[5];
    const float* b2   = (const float*)d_in[6];
    const float* W2r  = (const float*)d_in[7];
    float* out = (float*)d_out;

    // workspace layout (floats):
    //   xl   : [0       , 64N)
    //   xr   : [64N     , 128N)
    //   hl   : [128N    , 129N)
    //   hr   : [129N    , 130N)
    //   agg1 : [130N    , 194N)   -- zeroed
    //   deg  : [194N    , 195N)   -- zeroed (becomes deg_inv in place)
    //   agg2 : [195N    , 196N)   -- zeroed
    float* ws   = (float*)d_ws;
    const size_t N = N_NODES;
    float* xl   = ws;
    float* xr   = ws + 64 * N;
    float* hl   = ws + 128 * N;
    float* hr   = ws + 129 * N;
    float* agg1 = ws + 130 * N;
    float* deg  = ws + 194 * N;
    float* agg2 = ws + 195 * N;

    // zero agg1 + deg + agg2 in one contiguous memset (66N floats)
    hipMemsetAsync(agg1, 0, 66 * N * sizeof(float), stream);

    gemm1<<<(N_NODES + 7) / 8, 256, 0, stream>>>(x, W1l, W1r, b1, xl, xr);

    {
        const long long total = (long long)N_EDGES * 64;
        const int blocks = (int)((total + 255) / 256);
        scatter1<<<blocks, 256, 0, stream>>>(ei, xl, agg1, deg);
    }

    deginv<<<(N_NODES + 255) / 256, 256, 0, stream>>>(deg);

    {
        const long long total = (long long)N_NODES * 64;
        const int blocks = (int)((total + 255) / 256);
        nodeC<<<blocks, 256, 0, stream>>>(agg1, xr, deg, W2l, W2r, b2, hl, hr);
    }

    scatter2<<<(N_EDGES + 255) / 256, 256, 0, stream>>>(ei, hl, agg2);

    outk<<<(N_NODES + 255) / 256, 256, 0, stream>>>(agg2, deg, hr, out);
}

// Round 2
// 794.772 us; speedup vs baseline: 1.5122x; 1.5122x over previous
//
#include <hip/hip_runtime.h>
#include <math.h>

#define N_NODES 100000
#define N_EDGES 3200000
#define IN_DIM  128
#define HID     64
#define NB_SCAN ((N_NODES + 255) / 256)   // 391 scan blocks

// ---------------------------------------------------------------------------
// gemm1: xl = x @ W1_l ; xr = x @ W1_r + b1   (both N x 64)
// Weights live in one [128][128] LDS tile. 8 x-rows per block.
// ---------------------------------------------------------------------------
__global__ __launch_bounds__(256) void gemm1(const float* __restrict__ x,
                                             const float* __restrict__ Wl,
                                             const float* __restrict__ Wr,
                                             const float* __restrict__ b1,
                                             float* __restrict__ xl,
                                             float* __restrict__ xr) {
    __shared__ float Wc[IN_DIM][128];  // cols 0..63 = W1_l, 64..127 = W1_r
    const int tid = threadIdx.x;

    for (int idx = tid * 4; idx < IN_DIM * 128; idx += 256 * 4) {
        const int row = idx >> 7;
        const int col = idx & 127;
        float4 v;
        if (col < 64) v = *(const float4*)&Wl[row * 64 + col];
        else          v = *(const float4*)&Wr[row * 64 + (col - 64)];
        *(float4*)&Wc[row][col] = v;
    }
    __syncthreads();

    const int row  = tid >> 5;          // 0..7
    const int c4   = (tid & 31) * 4;    // 0,4,...,124
    const int node = blockIdx.x * 8 + row;
    if (node >= N_NODES) return;

    const float* xrow = x + (size_t)node * IN_DIM;
    float a0 = 0.f, a1 = 0.f, a2 = 0.f, a3 = 0.f;
    #pragma unroll 8
    for (int k = 0; k < IN_DIM; ++k) {
        const float xv = xrow[k];
        const float4 w = *(const float4*)&Wc[k][c4];
        a0 += xv * w.x; a1 += xv * w.y; a2 += xv * w.z; a3 += xv * w.w;
    }

    if (c4 < 64) {
        float4 o = {a0, a1, a2, a3};
        *(float4*)&xl[(size_t)node * HID + c4] = o;
    } else {
        const int c = c4 - 64;
        const float4 bb = *(const float4*)&b1[c];
        float4 o = {a0 + bb.x, a1 + bb.y, a2 + bb.z, a3 + bb.w};
        *(float4*)&xr[(size_t)node * HID + c] = o;
    }
}

// ---------------------------------------------------------------------------
// CSR build: histogram -> 2-level exclusive scan -> index scatter
// ---------------------------------------------------------------------------
__global__ __launch_bounds__(256) void hist(const int* __restrict__ ei,
                                            int* __restrict__ cnt) {
    const int e = blockIdx.x * 256 + threadIdx.x;
    if (e >= N_EDGES) return;
    atomicAdd(&cnt[ei[N_EDGES + e]], 1);
}

__global__ __launch_bounds__(256) void scanA(const int* __restrict__ cnt,
                                             int* __restrict__ incl,
                                             int* __restrict__ partial) {
    __shared__ int sh[256];
    const int tid = threadIdx.x;
    const int gid = blockIdx.x * 256 + tid;
    int v = (gid < N_NODES) ? cnt[gid] : 0;
    sh[tid] = v;
    __syncthreads();
    for (int off = 1; off < 256; off <<= 1) {
        int t = (tid >= off) ? sh[tid - off] : 0;
        __syncthreads();
        sh[tid] += t;
        __syncthreads();
    }
    if (gid < N_NODES) incl[gid] = sh[tid];
    if (tid == 255) partial[blockIdx.x] = sh[255];
}

__global__ __launch_bounds__(512) void scanB(int* __restrict__ partial) {
    __shared__ int sh[512];
    const int tid = threadIdx.x;
    int v = (tid < NB_SCAN) ? partial[tid] : 0;
    sh[tid] = v;
    __syncthreads();
    for (int off = 1; off < 512; off <<= 1) {
        int t = (tid >= off) ? sh[tid - off] : 0;
        __syncthreads();
        sh[tid] += t;
        __syncthreads();
    }
    if (tid < NB_SCAN) partial[tid] = sh[tid] - v;   // exclusive
}

__global__ __launch_bounds__(256) void scanC(const int* __restrict__ cnt,
                                             const int* __restrict__ incl,
                                             const int* __restrict__ partial,
                                             int* __restrict__ start,
                                             int* __restrict__ cursor,
                                             float* __restrict__ deg_inv) {
    const int gid = blockIdx.x * 256 + threadIdx.x;
    if (gid >= N_NODES) return;
    const int c = cnt[gid];
    const int s = incl[gid] - c + partial[blockIdx.x];
    start[gid]  = s;
    cursor[gid] = s;
    deg_inv[gid] = (c > 0) ? (1.0f / (float)c) : 0.0f;
}

__global__ __launch_bounds__(256) void scatterIdx(const int* __restrict__ ei,
                                                  int* __restrict__ cursor,
                                                  int* __restrict__ sorted_src) {
    const int e = blockIdx.x * 256 + threadIdx.x;
    if (e >= N_EDGES) return;
    const int pos = atomicAdd(&cursor[ei[N_EDGES + e]], 1);
    sorted_src[pos] = ei[e];
}

// ---------------------------------------------------------------------------
// agg1pull: wave per node. sum_{j in N(i)} xl[j] via CSR gather, then fused
// layer-1 epilogue: h = relu(sum*deg_inv + xr); hl = h.W2_l; hr = h.W2_r + b2
// ---------------------------------------------------------------------------
__global__ __launch_bounds__(256) void agg1pull(const int* __restrict__ start,
                                                const int* __restrict__ cnt,
                                                const int* __restrict__ sorted_src,
                                                const float* __restrict__ xl,
                                                const float* __restrict__ xr,
                                                const float* __restrict__ deg_inv,
                                                const float* __restrict__ w2l,
                                                const float* __restrict__ w2r,
                                                const float* __restrict__ b2,
                                                float* __restrict__ hl,
                                                float* __restrict__ hr) {
    const int gid  = blockIdx.x * 256 + threadIdx.x;
    const int node = gid >> 6;
    const int lane = gid & 63;
    if (node >= N_NODES) return;

    const int s = start[node];
    const int c = cnt[node];

    float sum = 0.0f;
    for (int base = 0; base < c; base += 64) {
        const int rem = c - base;
        const int m   = rem < 64 ? rem : 64;
        int my = 0;
        if (lane < m) my = sorted_src[s + base + lane];   // coalesced
        for (int j = 0; j < m; ++j) {
            const int src = __shfl(my, j);
            sum += xl[(size_t)src * HID + lane];          // coalesced 256B row
        }
    }

    float h = sum * deg_inv[node] + xr[(size_t)node * HID + lane];
    h = fmaxf(h, 0.0f);
    float a = h * w2l[lane];
    float b = h * w2r[lane];
    #pragma unroll
    for (int off = 32; off; off >>= 1) {
        a += __shfl_xor(a, off);
        b += __shfl_xor(b, off);
    }
    if (lane == 0) {
        hl[node] = a;
        hr[node] = b + b2[0];
    }
}

// ---------------------------------------------------------------------------
// agg2pull: wave per node. out = sigmoid(sum_{j} hl[j] * deg_inv + hr)
// ---------------------------------------------------------------------------
__global__ __launch_bounds__(256) void agg2pull(const int* __restrict__ start,
                                                const int* __restrict__ cnt,
                                                const int* __restrict__ sorted_src,
                                                const float* __restrict__ hl,
                                                const float* __restrict__ hr,
                                                const float* __restrict__ deg_inv,
                                                float* __restrict__ out) {
    const int gid  = blockIdx.x * 256 + threadIdx.x;
    const int node = gid >> 6;
    const int lane = gid & 63;
    if (node >= N_NODES) return;

    const int s = start[node];
    const int c = cnt[node];

    float sum = 0.0f;
    for (int j = lane; j < c; j += 64) {
        sum += hl[sorted_src[s + j]];
    }
    #pragma unroll
    for (int off = 32; off; off >>= 1) sum += __shfl_xor(sum, off);

    if (lane == 0) {
        const float z = sum * deg_inv[node] + hr[node];
        out[node] = 1.0f / (1.0f + expf(-z));
    }
}

extern "C" void kernel_launch(void* const* d_in, const int* in_sizes, int n_in,
                              void* d_out, int out_size, void* d_ws, size_t ws_size,
                              hipStream_t stream) {
    const float* x    = (const float*)d_in[0];
    const int*   ei   = (const int*)  d_in[1];
    const float* W1l  = (const float*)d_in[2];
    const float* b1   = (const float*)d_in[3];
    const float* W1r  = (const float*)d_in[4];
    const float* W2l  = (const float*)d_in[5];
    const float* b2   = (const float*)d_in[6];
    const float* W2r  = (const float*)d_in[7];
    float* out = (float*)d_out;

    // workspace layout (4-byte elems):
    //   xl         : [0,        6.4M)  float
    //   xr         : [6.4M,    12.8M)  float
    //   hl         : 100K float
    //   hr         : 100K float
    //   deg_inv    : 100K float
    //   cnt        : 100K int   (zeroed)
    //   incl       : 100K int
    //   start      : 100K int
    //   cursor     : 100K int
    //   partial    : 512  int
    //   sorted_src : 3.2M int
    char* wsb = (char*)d_ws;
    const size_t N = N_NODES;
    float* xl       = (float*)wsb;                       wsb += 64 * N * 4;
    float* xr       = (float*)wsb;                       wsb += 64 * N * 4;
    float* hl       = (float*)wsb;                       wsb += N * 4;
    float* hr       = (float*)wsb;                       wsb += N * 4;
    float* deg_inv  = (float*)wsb;                       wsb += N * 4;
    int*   cnt      = (int*)wsb;                         wsb += N * 4;
    int*   incl     = (int*)wsb;                         wsb += N * 4;
    int*   startA   = (int*)wsb;                         wsb += N * 4;
    int*   cursor   = (int*)wsb;                         wsb += N * 4;
    int*   partial  = (int*)wsb;                         wsb += 512 * 4;
    int*   ssrc     = (int*)wsb;                         wsb += (size_t)N_EDGES * 4;

    hipMemsetAsync(cnt, 0, N * sizeof(int), stream);

    gemm1<<<(N_NODES + 7) / 8, 256, 0, stream>>>(x, W1l, W1r, b1, xl, xr);

    const int eb = (N_EDGES + 255) / 256;
    hist<<<eb, 256, 0, stream>>>(ei, cnt);
    scanA<<<NB_SCAN, 256, 0, stream>>>(cnt, incl, partial);
    scanB<<<1, 512, 0, stream>>>(partial);
    scanC<<<NB_SCAN, 256, 0, stream>>>(cnt, incl, partial, startA, cursor, deg_inv);
    scatterIdx<<<eb, 256, 0, stream>>>(ei, cursor, ssrc);

    {
        const long long total = (long long)N_NODES * 64;
        const int blocks = (int)((total + 255) / 256);
        agg1pull<<<blocks, 256, 0, stream>>>(startA, cnt, ssrc, xl, xr, deg_inv,
                                             W2l, W2r, b2, hl, hr);
        agg2pull<<<blocks, 256, 0, stream>>>(startA, cnt, ssrc, hl, hr, deg_inv, out);
    }
}

// Round 3
// 504.109 us; speedup vs baseline: 2.3842x; 1.5766x over previous
//
#include <hip/hip_runtime.h>
#include <math.h>

#define N_NODES 100000
#define N_EDGES 3200000
#define IN_DIM  128
#define HID     64
#define NB_SCAN ((N_NODES + 255) / 256)   // 391 scan blocks

typedef unsigned int uint;

// round-to-nearest-even bf16 pack: lo -> bits[15:0], hi -> bits[31:16]
__device__ __forceinline__ uint bfpack(float lo, float hi) {
    uint a = __float_as_uint(lo);
    uint b = __float_as_uint(hi);
    a = (a + 0x7fffu + ((a >> 16) & 1u)) >> 16;
    b = (b + 0x7fffu + ((b >> 16) & 1u)) & 0xffff0000u;
    return a | b;
}

// ---------------------------------------------------------------------------
// gemm1: xlb = bf16pack(x @ W1_l)  (N x 32 uints, 2 cols per uint)
//        xr  = x @ W1_r + b1      (N x 64 f32)
// ---------------------------------------------------------------------------
__global__ __launch_bounds__(256) void gemm1(const float* __restrict__ x,
                                             const float* __restrict__ Wl,
                                             const float* __restrict__ Wr,
                                             const float* __restrict__ b1,
                                             uint* __restrict__ xlb,
                                             float* __restrict__ xr) {
    __shared__ float Wc[IN_DIM][128];  // cols 0..63 = W1_l, 64..127 = W1_r
    const int tid = threadIdx.x;

    for (int idx = tid * 4; idx < IN_DIM * 128; idx += 256 * 4) {
        const int row = idx >> 7;
        const int col = idx & 127;
        float4 v;
        if (col < 64) v = *(const float4*)&Wl[row * 64 + col];
        else          v = *(const float4*)&Wr[row * 64 + (col - 64)];
        *(float4*)&Wc[row][col] = v;
    }
    __syncthreads();

    const int row  = tid >> 5;          // 0..7
    const int c4   = (tid & 31) * 4;    // 0,4,...,124
    const int node = blockIdx.x * 8 + row;
    if (node >= N_NODES) return;

    const float* xrow = x + (size_t)node * IN_DIM;
    float a0 = 0.f, a1 = 0.f, a2 = 0.f, a3 = 0.f;
    #pragma unroll 8
    for (int k = 0; k < IN_DIM; ++k) {
        const float xv = xrow[k];
        const float4 w = *(const float4*)&Wc[k][c4];
        a0 += xv * w.x; a1 += xv * w.y; a2 += xv * w.z; a3 += xv * w.w;
    }

    if (c4 < 64) {
        uint2 p = { bfpack(a0, a1), bfpack(a2, a3) };
        *(uint2*)&xlb[(size_t)node * 32 + (c4 >> 1)] = p;
    } else {
        const int c = c4 - 64;
        const float4 bb = *(const float4*)&b1[c];
        float4 o = {a0 + bb.x, a1 + bb.y, a2 + bb.z, a3 + bb.w};
        *(float4*)&xr[(size_t)node * HID + c] = o;
    }
}

// ---------------------------------------------------------------------------
// hist: cnt[dst]++ and remember each edge's rank within its dst bucket
// ---------------------------------------------------------------------------
__global__ __launch_bounds__(256) void hist(const int* __restrict__ ei,
                                            int* __restrict__ cnt,
                                            int* __restrict__ rank) {
    const int e = blockIdx.x * 256 + threadIdx.x;
    if (e >= N_EDGES) return;
    rank[e] = atomicAdd(&cnt[ei[N_EDGES + e]], 1);
}

__global__ __launch_bounds__(256) void scanA(const int* __restrict__ cnt,
                                             int* __restrict__ incl,
                                             int* __restrict__ partial) {
    __shared__ int sh[256];
    const int tid = threadIdx.x;
    const int gid = blockIdx.x * 256 + tid;
    int v = (gid < N_NODES) ? cnt[gid] : 0;
    sh[tid] = v;
    __syncthreads();
    for (int off = 1; off < 256; off <<= 1) {
        int t = (tid >= off) ? sh[tid - off] : 0;
        __syncthreads();
        sh[tid] += t;
        __syncthreads();
    }
    if (gid < N_NODES) incl[gid] = sh[tid];
    if (tid == 255) partial[blockIdx.x] = sh[255];
}

__global__ __launch_bounds__(512) void scanB(int* __restrict__ partial) {
    __shared__ int sh[512];
    const int tid = threadIdx.x;
    int v = (tid < NB_SCAN) ? partial[tid] : 0;
    sh[tid] = v;
    __syncthreads();
    for (int off = 1; off < 512; off <<= 1) {
        int t = (tid >= off) ? sh[tid - off] : 0;
        __syncthreads();
        sh[tid] += t;
        __syncthreads();
    }
    if (tid < NB_SCAN) partial[tid] = sh[tid] - v;   // exclusive
}

__global__ __launch_bounds__(256) void scanC(const int* __restrict__ cnt,
                                             const int* __restrict__ incl,
                                             const int* __restrict__ partial,
                                             int* __restrict__ start,
                                             float* __restrict__ deg_inv) {
    const int gid = blockIdx.x * 256 + threadIdx.x;
    if (gid >= N_NODES) return;
    const int c = cnt[gid];
    start[gid]  = incl[gid] - c + partial[blockIdx.x];
    deg_inv[gid] = (c > 0) ? (1.0f / (float)c) : 0.0f;
}

// ---------------------------------------------------------------------------
// scatterIdx: no atomics — pos precomputed from hist rank + scanned start
// ---------------------------------------------------------------------------
__global__ __launch_bounds__(256) void scatterIdx(const int* __restrict__ ei,
                                                  const int* __restrict__ start,
                                                  const int* __restrict__ rank,
                                                  int* __restrict__ sorted_src) {
    const int e = blockIdx.x * 256 + threadIdx.x;
    if (e >= N_EDGES) return;
    const int dst = ei[N_EDGES + e];
    sorted_src[start[dst] + rank[e]] = ei[e];
}

// ---------------------------------------------------------------------------
// agg1pull: wave per node; 2 neighbor rows per iteration (uint = 2 bf16/lane).
// Fused epilogue: h = relu(sum*deg_inv + xr); hl = h.W2_l; hr = h.W2_r + b2
// ---------------------------------------------------------------------------
__global__ __launch_bounds__(256) void agg1pull(const int* __restrict__ start,
                                                const int* __restrict__ cnt,
                                                const int* __restrict__ sorted_src,
                                                const uint* __restrict__ xlb,
                                                const float* __restrict__ xr,
                                                const float* __restrict__ deg_inv,
                                                const float* __restrict__ w2l,
                                                const float* __restrict__ w2r,
                                                const float* __restrict__ b2,
                                                float* __restrict__ hl,
                                                float* __restrict__ hr) {
    const int gid  = blockIdx.x * 256 + threadIdx.x;
    const int node = gid >> 6;
    const int lane = gid & 63;
    if (node >= N_NODES) return;

    const int s    = start[node];
    const int c    = cnt[node];
    const int half = lane >> 5;      // which neighbor of the pair
    const int col2 = lane & 31;      // uint index within the 32-uint row

    float sx = 0.0f, sy = 0.0f;
    for (int base = 0; base < c; base += 64) {
        const int rem = c - base;
        const int m   = rem < 64 ? rem : 64;
        int my = 0;
        if (lane < m) my = sorted_src[s + base + lane];   // coalesced
        for (int jj = 0; jj < m; jj += 2) {
            const int  src0 = __shfl(my, jj);
            const bool has1 = (jj + 1) < m;
            const int  src1 = has1 ? __shfl(my, jj + 1) : src0;
            const int  srcp = half ? src1 : src0;
            if (half == 0 || has1) {
                const uint v = xlb[(size_t)srcp * 32 + col2];  // 128B/row, 2 rows/iter
                sx += __uint_as_float(v << 16);
                sy += __uint_as_float(v & 0xffff0000u);
            }
        }
    }
    // fold the two half-wave partial sums
    sx += __shfl_xor(sx, 32);
    sy += __shfl_xor(sy, 32);

    const float di  = deg_inv[node];
    const float2 xv = *(const float2*)&xr[(size_t)node * HID + 2 * col2];
    const float h0  = fmaxf(sx * di + xv.x, 0.0f);
    const float h1  = fmaxf(sy * di + xv.y, 0.0f);
    float a = h0 * w2l[2 * col2] + h1 * w2l[2 * col2 + 1];
    float b = h0 * w2r[2 * col2] + h1 * w2r[2 * col2 + 1];
    #pragma unroll
    for (int off = 16; off; off >>= 1) {
        a += __shfl_xor(a, off);
        b += __shfl_xor(b, off);
    }
    if (lane == 0) {
        hl[node] = a;
        hr[node] = b + b2[0];
    }
}

// ---------------------------------------------------------------------------
// agg2pull: wave per node. out = sigmoid(sum_j hl[j] * deg_inv + hr)
// ---------------------------------------------------------------------------
__global__ __launch_bounds__(256) void agg2pull(const int* __restrict__ start,
                                                const int* __restrict__ cnt,
                                                const int* __restrict__ sorted_src,
                                                const float* __restrict__ hl,
                                                const float* __restrict__ hr,
                                                const float* __restrict__ deg_inv,
                                                float* __restrict__ out) {
    const int gid  = blockIdx.x * 256 + threadIdx.x;
    const int node = gid >> 6;
    const int lane = gid & 63;
    if (node >= N_NODES) return;

    const int s = start[node];
    const int c = cnt[node];

    float sum = 0.0f;
    for (int j = lane; j < c; j += 64) {
        sum += hl[sorted_src[s + j]];
    }
    #pragma unroll
    for (int off = 32; off; off >>= 1) sum += __shfl_xor(sum, off);

    if (lane == 0) {
        const float z = sum * deg_inv[node] + hr[node];
        out[node] = 1.0f / (1.0f + expf(-z));
    }
}

extern "C" void kernel_launch(void* const* d_in, const int* in_sizes, int n_in,
                              void* d_out, int out_size, void* d_ws, size_t ws_size,
                              hipStream_t stream) {
    const float* x    = (const float*)d_in[0];
    const int*   ei   = (const int*)  d_in[1];
    const float* W1l  = (const float*)d_in[2];
    const float* b1   = (const float*)d_in[3];
    const float* W1r  = (const float*)d_in[4];
    const float* W2l  = (const float*)d_in[5];
    const float* b2   = (const float*)d_in[6];
    const float* W2r  = (const float*)d_in[7];
    float* out = (float*)d_out;

    // workspace layout (bytes):
    //   xlb        : N*32 uint  (12.8 MB, bf16-packed xl)
    //   xr         : N*64 f32   (25.6 MB)
    //   hl, hr     : N f32 each
    //   deg_inv    : N f32
    //   cnt        : N int   (zeroed)
    //   incl       : N int
    //   start      : N int
    //   rank       : E int   (12.8 MB)
    //   partial    : 512 int
    //   sorted_src : E int   (12.8 MB)
    char* wsb = (char*)d_ws;
    const size_t N = N_NODES;
    uint*  xlb      = (uint*)wsb;                        wsb += 32 * N * 4;
    float* xr       = (float*)wsb;                       wsb += 64 * N * 4;
    float* hl       = (float*)wsb;                       wsb += N * 4;
    float* hr       = (float*)wsb;                       wsb += N * 4;
    float* deg_inv  = (float*)wsb;                       wsb += N * 4;
    int*   cnt      = (int*)wsb;                         wsb += N * 4;
    int*   incl     = (int*)wsb;                         wsb += N * 4;
    int*   startA   = (int*)wsb;                         wsb += N * 4;
    int*   rank     = (int*)wsb;                         wsb += (size_t)N_EDGES * 4;
    int*   partial  = (int*)wsb;                         wsb += 512 * 4;
    int*   ssrc     = (int*)wsb;                         wsb += (size_t)N_EDGES * 4;

    hipMemsetAsync(cnt, 0, N * sizeof(int), stream);

    gemm1<<<(N_NODES + 7) / 8, 256, 0, stream>>>(x, W1l, W1r, b1, xlb, xr);

    const int eb = (N_EDGES + 255) / 256;
    hist<<<eb, 256, 0, stream>>>(ei, cnt, rank);
    scanA<<<NB_SCAN, 256, 0, stream>>>(cnt, incl, partial);
    scanB<<<1, 512, 0, stream>>>(partial);
    scanC<<<NB_SCAN, 256, 0, stream>>>(cnt, incl, partial, startA, deg_inv);
    scatterIdx<<<eb, 256, 0, stream>>>(ei, startA, rank, ssrc);

    {
        const long long total = (long long)N_NODES * 64;
        const int blocks = (int)((total + 255) / 256);
        agg1pull<<<blocks, 256, 0, stream>>>(startA, cnt, ssrc, xlb, xr, deg_inv,
                                             W2l, W2r, b2, hl, hr);
        agg2pull<<<blocks, 256, 0, stream>>>(startA, cnt, ssrc, hl, hr, deg_inv, out);
    }
}

// Round 4
// 375.791 us; speedup vs baseline: 3.1983x; 1.3415x over previous
//
#include <hip/hip_runtime.h>
#include <math.h>

#define N_NODES 100000
#define N_EDGES 3200000
#define IN_DIM  128
#define HID     64
#define NB_SCAN ((N_NODES + 255) / 256)   // 391 scan blocks
#define N_MTILE (N_NODES / 16)            // 6250 row-tiles (exact)

typedef unsigned int  uint;
typedef unsigned short ushort_t;
typedef __attribute__((ext_vector_type(8))) short bf16x8;
typedef __attribute__((ext_vector_type(4))) float f32x4;

// round-to-nearest-even bf16 pack: lo -> bits[15:0], hi -> bits[31:16]
__device__ __forceinline__ uint bfpack(float lo, float hi) {
    uint a = __float_as_uint(lo);
    uint b = __float_as_uint(hi);
    a = (a + 0x7fffu + ((a >> 16) & 1u)) >> 16;
    b = (b + 0x7fffu + ((b >> 16) & 1u)) & 0xffff0000u;
    return a | b;
}

// HW packed f32->bf16 (RNE): lo -> bits[15:0], hi -> bits[31:16]
__device__ __forceinline__ uint cvtpk(float lo, float hi) {
    uint r;
    asm("v_cvt_pk_bf16_f32 %0, %1, %2" : "=v"(r) : "v"(lo), "v"(hi));
    return r;
}

// ---------------------------------------------------------------------------
// wrepack: lay W = [W1_l | W1_r] (128x128) out in per-lane B-fragment order
// for v_mfma_f32_16x16x32_bf16:
//   wpk[(((t*4 + s)*64 + l)*8 + j)] = bf16( W[s*32 + (l>>4)*8 + j][t*16 + (l&15)] )
// t = col-tile 0..7, s = k-step 0..3, l = lane, j = k-elem 0..7
// ---------------------------------------------------------------------------
__global__ __launch_bounds__(256) void wrepack(const float* __restrict__ Wl,
                                               const float* __restrict__ Wr,
                                               ushort_t* __restrict__ wpk) {
    const int idx = blockIdx.x * 256 + threadIdx.x;
    if (idx >= 128 * 128) return;
    const int j = idx & 7;
    const int l = (idx >> 3) & 63;
    const int s = (idx >> 9) & 3;
    const int t = idx >> 11;
    const int row = s * 32 + ((l >> 4) << 3) + j;
    const int col = t * 16 + (l & 15);
    const float v = (col < 64) ? Wl[row * 64 + col] : Wr[row * 64 + (col - 64)];
    uint a = __float_as_uint(v);
    a = (a + 0x7fffu + ((a >> 16) & 1u)) >> 16;
    wpk[idx] = (ushort_t)a;
}

// ---------------------------------------------------------------------------
// gemm1m: MFMA gemm. Block = 4 waves, all on the same 16-row A-tile.
// Wave w owns col-tiles {2w, 2w+1}: waves 0,1 -> xlb (bf16 packed),
// waves 2,3 -> xr (+b1, f32). B-fragments live in 32 VGPRs for the whole
// kernel (loaded once); A loaded as 2 x float4 per k-step and cvt_pk'd.
// ---------------------------------------------------------------------------
__global__ __launch_bounds__(256) void gemm1m(const float* __restrict__ x,
                                              const ushort_t* __restrict__ wpk,
                                              const float* __restrict__ b1,
                                              uint* __restrict__ xlb,
                                              float* __restrict__ xr) {
    const int tid  = threadIdx.x;
    const int wid  = tid >> 6;
    const int lane = tid & 63;
    const int t0   = wid * 2;
    const int r16  = lane & 15;   // A-row / C-col within tile
    const int kg   = lane >> 4;   // k-group

    // B-fragments: 2 tiles x 4 k-steps x 4 VGPRs
    bf16x8 bf[2][4];
    #pragma unroll
    for (int tt = 0; tt < 2; ++tt)
        #pragma unroll
        for (int s = 0; s < 4; ++s)
            bf[tt][s] = *(const bf16x8*)&wpk[(((size_t)(t0 + tt) * 4 + s) * 64 + lane) * 8];

    // bias for xr waves (col = (t0+tt)*16 + r16 - 64)
    float bias[2] = {0.f, 0.f};
    if (wid >= 2) {
        bias[0] = b1[(t0 + 0) * 16 + r16 - 64];
        bias[1] = b1[(t0 + 1) * 16 + r16 - 64];
    }

    for (int tile = blockIdx.x; tile < N_MTILE; tile += gridDim.x) {
        const int row0 = tile * 16;
        const float* ap = x + (size_t)(row0 + r16) * IN_DIM + kg * 8;

        f32x4 acc[2];
        acc[0] = (f32x4){0.f, 0.f, 0.f, 0.f};
        acc[1] = (f32x4){0.f, 0.f, 0.f, 0.f};

        #pragma unroll
        for (int s = 0; s < 4; ++s) {
            const f32x4 a0 = *(const f32x4*)(ap + s * 32);
            const f32x4 a1 = *(const f32x4*)(ap + s * 32 + 4);
            union { uint u[4]; bf16x8 v; } af;
            af.u[0] = cvtpk(a0.x, a0.y);
            af.u[1] = cvtpk(a0.z, a0.w);
            af.u[2] = cvtpk(a1.x, a1.y);
            af.u[3] = cvtpk(a1.z, a1.w);
            acc[0] = __builtin_amdgcn_mfma_f32_16x16x32_bf16(af.v, bf[0][s], acc[0], 0, 0, 0);
            acc[1] = __builtin_amdgcn_mfma_f32_16x16x32_bf16(af.v, bf[1][s], acc[1], 0, 0, 0);
        }

        if (wid < 2) {
            // xl columns: pack adjacent col pairs (adjacent lanes) to bf16x2
            #pragma unroll
            for (int tt = 0; tt < 2; ++tt) {
                const int col = (t0 + tt) * 16 + r16;
                #pragma unroll
                for (int r = 0; r < 4; ++r) {
                    const float mine  = acc[tt][r];
                    const float other = __shfl_xor(mine, 1);
                    if ((lane & 1) == 0) {
                        const int row = row0 + kg * 4 + r;
                        xlb[(size_t)row * 32 + (col >> 1)] = cvtpk(mine, other);
                    }
                }
            }
        } else {
            #pragma unroll
            for (int tt = 0; tt < 2; ++tt) {
                const int c = (t0 + tt) * 16 + r16 - 64;
                #pragma unroll
                for (int r = 0; r < 4; ++r) {
                    const int row = row0 + kg * 4 + r;
                    xr[(size_t)row * HID + c] = acc[tt][r] + bias[tt];
                }
            }
        }
    }
}

// ---------------------------------------------------------------------------
// hist: cnt[dst]++ and remember each edge's rank within its dst bucket
// ---------------------------------------------------------------------------
__global__ __launch_bounds__(256) void hist(const int* __restrict__ ei,
                                            int* __restrict__ cnt,
                                            int* __restrict__ rank) {
    const int e = blockIdx.x * 256 + threadIdx.x;
    if (e >= N_EDGES) return;
    rank[e] = atomicAdd(&cnt[ei[N_EDGES + e]], 1);
}

__global__ __launch_bounds__(256) void scanA(const int* __restrict__ cnt,
                                             int* __restrict__ incl,
                                             int* __restrict__ partial) {
    __shared__ int sh[256];
    const int tid = threadIdx.x;
    const int gid = blockIdx.x * 256 + tid;
    int v = (gid < N_NODES) ? cnt[gid] : 0;
    sh[tid] = v;
    __syncthreads();
    for (int off = 1; off < 256; off <<= 1) {
        int t = (tid >= off) ? sh[tid - off] : 0;
        __syncthreads();
        sh[tid] += t;
        __syncthreads();
    }
    if (gid < N_NODES) incl[gid] = sh[tid];
    if (tid == 255) partial[blockIdx.x] = sh[255];
}

__global__ __launch_bounds__(512) void scanB(int* __restrict__ partial) {
    __shared__ int sh[512];
    const int tid = threadIdx.x;
    int v = (tid < NB_SCAN) ? partial[tid] : 0;
    sh[tid] = v;
    __syncthreads();
    for (int off = 1; off < 512; off <<= 1) {
        int t = (tid >= off) ? sh[tid - off] : 0;
        __syncthreads();
        sh[tid] += t;
        __syncthreads();
    }
    if (tid < NB_SCAN) partial[tid] = sh[tid] - v;   // exclusive
}

__global__ __launch_bounds__(256) void scanC(const int* __restrict__ cnt,
                                             const int* __restrict__ incl,
                                             const int* __restrict__ partial,
                                             int* __restrict__ start,
                                             float* __restrict__ deg_inv) {
    const int gid = blockIdx.x * 256 + threadIdx.x;
    if (gid >= N_NODES) return;
    const int c = cnt[gid];
    start[gid]  = incl[gid] - c + partial[blockIdx.x];
    deg_inv[gid] = (c > 0) ? (1.0f / (float)c) : 0.0f;
}

// ---------------------------------------------------------------------------
// scatterIdx: no atomics — pos precomputed from hist rank + scanned start
// ---------------------------------------------------------------------------
__global__ __launch_bounds__(256) void scatterIdx(const int* __restrict__ ei,
                                                  const int* __restrict__ start,
                                                  const int* __restrict__ rank,
                                                  int* __restrict__ sorted_src) {
    const int e = blockIdx.x * 256 + threadIdx.x;
    if (e >= N_EDGES) return;
    const int dst = ei[N_EDGES + e];
    sorted_src[start[dst] + rank[e]] = ei[e];
}

// ---------------------------------------------------------------------------
// agg1pull: wave per node; 2 neighbor rows per iteration (uint = 2 bf16/lane).
// Fused epilogue: h = relu(sum*deg_inv + xr); hl = h.W2_l; hr = h.W2_r + b2
// ---------------------------------------------------------------------------
__global__ __launch_bounds__(256) void agg1pull(const int* __restrict__ start,
                                                const int* __restrict__ cnt,
                                                const int* __restrict__ sorted_src,
                                                const uint* __restrict__ xlb,
                                                const float* __restrict__ xr,
                                                const float* __restrict__ deg_inv,
                                                const float* __restrict__ w2l,
                                                const float* __restrict__ w2r,
                                                const float* __restrict__ b2,
                                                float* __restrict__ hl,
                                                float* __restrict__ hr) {
    const int gid  = blockIdx.x * 256 + threadIdx.x;
    const int node = gid >> 6;
    const int lane = gid & 63;
    if (node >= N_NODES) return;

    const int s    = start[node];
    const int c    = cnt[node];
    const int half = lane >> 5;
    const int col2 = lane & 31;

    float sx = 0.0f, sy = 0.0f;
    for (int base = 0; base < c; base += 64) {
        const int rem = c - base;
        const int m   = rem < 64 ? rem : 64;
        int my = 0;
        if (lane < m) my = sorted_src[s + base + lane];
        for (int jj = 0; jj < m; jj += 2) {
            const int  src0 = __shfl(my, jj);
            const bool has1 = (jj + 1) < m;
            const int  src1 = has1 ? __shfl(my, jj + 1) : src0;
            const int  srcp = half ? src1 : src0;
            if (half == 0 || has1) {
                const uint v = xlb[(size_t)srcp * 32 + col2];
                sx += __uint_as_float(v << 16);
                sy += __uint_as_float(v & 0xffff0000u);
            }
        }
    }
    sx += __shfl_xor(sx, 32);
    sy += __shfl_xor(sy, 32);

    const float di  = deg_inv[node];
    const float2 xv = *(const float2*)&xr[(size_t)node * HID + 2 * col2];
    const float h0  = fmaxf(sx * di + xv.x, 0.0f);
    const float h1  = fmaxf(sy * di + xv.y, 0.0f);
    float a = h0 * w2l[2 * col2] + h1 * w2l[2 * col2 + 1];
    float b = h0 * w2r[2 * col2] + h1 * w2r[2 * col2 + 1];
    #pragma unroll
    for (int off = 16; off; off >>= 1) {
        a += __shfl_xor(a, off);
        b += __shfl_xor(b, off);
    }
    if (lane == 0) {
        hl[node] = a;
        hr[node] = b + b2[0];
    }
}

// ---------------------------------------------------------------------------
// agg2pull: wave per node. out = sigmoid(sum_j hl[j] * deg_inv + hr)
// ---------------------------------------------------------------------------
__global__ __launch_bounds__(256) void agg2pull(const int* __restrict__ start,
                                                const int* __restrict__ cnt,
                                                const int* __restrict__ sorted_src,
                                                const float* __restrict__ hl,
                                                const float* __restrict__ hr,
                                                const float* __restrict__ deg_inv,
                                                float* __restrict__ out) {
    const int gid  = blockIdx.x * 256 + threadIdx.x;
    const int node = gid >> 6;
    const int lane = gid & 63;
    if (node >= N_NODES) return;

    const int s = start[node];
    const int c = cnt[node];

    float sum = 0.0f;
    for (int j = lane; j < c; j += 64) {
        sum += hl[sorted_src[s + j]];
    }
    #pragma unroll
    for (int off = 32; off; off >>= 1) sum += __shfl_xor(sum, off);

    if (lane == 0) {
        const float z = sum * deg_inv[node] + hr[node];
        out[node] = 1.0f / (1.0f + expf(-z));
    }
}

extern "C" void kernel_launch(void* const* d_in, const int* in_sizes, int n_in,
                              void* d_out, int out_size, void* d_ws, size_t ws_size,
                              hipStream_t stream) {
    const float* x    = (const float*)d_in[0];
    const int*   ei   = (const int*)  d_in[1];
    const float* W1l  = (const float*)d_in[2];
    const float* b1   = (const float*)d_in[3];
    const float* W1r  = (const float*)d_in[4];
    const float* W2l  = (const float*)d_in[5];
    const float* b2   = (const float*)d_in[6];
    const float* W2r  = (const float*)d_in[7];
    float* out = (float*)d_out;

    char* wsb = (char*)d_ws;
    const size_t N = N_NODES;
    uint*     xlb     = (uint*)wsb;                      wsb += 32 * N * 4;
    float*    xr      = (float*)wsb;                     wsb += 64 * N * 4;
    float*    hl      = (float*)wsb;                     wsb += N * 4;
    float*    hr      = (float*)wsb;                     wsb += N * 4;
    float*    deg_inv = (float*)wsb;                     wsb += N * 4;
    int*      cnt     = (int*)wsb;                       wsb += N * 4;
    int*      incl    = (int*)wsb;                       wsb += N * 4;
    int*      startA  = (int*)wsb;                       wsb += N * 4;
    int*      rank    = (int*)wsb;                       wsb += (size_t)N_EDGES * 4;
    int*      partial = (int*)wsb;                       wsb += 512 * 4;
    int*      ssrc    = (int*)wsb;                       wsb += (size_t)N_EDGES * 4;
    ushort_t* wpk     = (ushort_t*)wsb;                  wsb += 128 * 128 * 2;

    hipMemsetAsync(cnt, 0, N * sizeof(int), stream);

    wrepack<<<64, 256, 0, stream>>>(W1l, W1r, wpk);
    gemm1m<<<2080, 256, 0, stream>>>(x, wpk, b1, xlb, xr);

    const int eb = (N_EDGES + 255) / 256;
    hist<<<eb, 256, 0, stream>>>(ei, cnt, rank);
    scanA<<<NB_SCAN, 256, 0, stream>>>(cnt, incl, partial);
    scanB<<<1, 512, 0, stream>>>(partial);
    scanC<<<NB_SCAN, 256, 0, stream>>>(cnt, incl, partial, startA, deg_inv);
    scatterIdx<<<eb, 256, 0, stream>>>(ei, startA, rank, ssrc);

    {
        const long long total = (long long)N_NODES * 64;
        const int blocks = (int)((total + 255) / 256);
        agg1pull<<<blocks, 256, 0, stream>>>(startA, cnt, ssrc, xlb, xr, deg_inv,
                                             W2l, W2r, b2, hl, hr);
        agg2pull<<<blocks, 256, 0, stream>>>(startA, cnt, ssrc, hl, hr, deg_inv, out);
    }
}